// Round 9
// baseline (1832.870 us; speedup 1.0000x reference)
//
#include <hip/hip_runtime.h>

#define NN   100000
#define NE   1600000
#define DD   64
#define LL   4
#define GG   512
#define OUTC 10
#define EPSV 1e-5f
#define PARTSZ 12500   // NN/8 dst-partition size

// workspace layout (float offsets). Total 14,631,088 floats = 58.5 MB.
#define OFF_RS    0          // int row_start[NN+1]
#define OFF_CSR   100016     // int csr_src[NE]   (first NN ints double as scan temp 'loc')
#define OFF_BUFA  1700016    // bf16 t ping (uses half the region; z1/sums/scan temps overlay)
#define OFF_BUFB  8100016    // bf16 t pong
#define OFF_POOL  14500016   // float pooled[GG*LL*DD]; deg/cnt(int[NN]) overlay pre-layers

static __device__ __forceinline__ unsigned short f2bf(float f) {
    unsigned int u = __float_as_uint(f);
    unsigned int r = (u + 0x7fffu + ((u >> 16) & 1u)) >> 16;   // RNE, finite inputs
    return (unsigned short)r;
}
static __device__ __forceinline__ float bf2f(unsigned short h) {
    return __uint_as_float(((unsigned int)h) << 16);
}

// ---- CSR build: XCD-partitioned histogram + fill ----
__global__ void deg_part_kernel(const int* __restrict__ dst, int* __restrict__ deg) {
    int p   = blockIdx.x & 7;
    int sub = blockIdx.x >> 3;
    int nb  = gridDim.x >> 3;
    for (int e = sub * 256 + threadIdx.x; e < NE; e += nb * 256) {
        int d = dst[e];
        if (d / PARTSZ == p) atomicAdd(&deg[d], 1);
    }
}

__global__ void scan1_kernel(const int* __restrict__ deg, int* __restrict__ loc,
                             int* __restrict__ bsum) {
    int t = threadIdx.x;
    int i = blockIdx.x * 1024 + t;
    int v = (i < NN) ? deg[i] : 0;
    __shared__ int ps[1024];
    ps[t] = v;
    __syncthreads();
    #pragma unroll
    for (int off = 1; off < 1024; off <<= 1) {
        int u = (t >= off) ? ps[t - off] : 0;
        __syncthreads();
        ps[t] += u;
        __syncthreads();
    }
    if (i < NN) loc[i] = ps[t] - v;
    if (t == 1023) bsum[blockIdx.x] = ps[1023];
}

__global__ void scan2_kernel(const int* __restrict__ bsum, int* __restrict__ boff) {
    int t = threadIdx.x;                      // 128 threads, 98 valid
    int v = (t < 98) ? bsum[t] : 0;
    __shared__ int ps[128];
    ps[t] = v;
    __syncthreads();
    #pragma unroll
    for (int off = 1; off < 128; off <<= 1) {
        int u = (t >= off) ? ps[t - off] : 0;
        __syncthreads();
        ps[t] += u;
        __syncthreads();
    }
    if (t < 98) boff[t] = ps[t] - v;
    if (t == 127) boff[98] = ps[127];
}

__global__ void scan3_kernel(const int* __restrict__ loc, const int* __restrict__ boff,
                             int* __restrict__ rs) {
    int i = blockIdx.x * 1024 + threadIdx.x;
    if (i < NN) rs[i] = loc[i] + boff[i >> 10];
    if (i == NN) rs[NN] = boff[98];
}

__global__ void fill_part_kernel(const int* __restrict__ src, const int* __restrict__ dst,
                                 const int* __restrict__ rs, int* __restrict__ cnt,
                                 int* __restrict__ csr) {
    int p   = blockIdx.x & 7;
    int sub = blockIdx.x >> 3;
    int nb  = gridDim.x >> 3;
    for (int e = sub * 256 + threadIdx.x; e < NE; e += nb * 256) {
        int d = dst[e];
        if (d / PARTSZ == p) {
            int slot = rs[d] + atomicAdd(&cnt[d], 1);
            csr[slot] = src[e];
        }
    }
}

// t0 = bf16(x * deg^{-1/2}); 4 elements/thread
__global__ void t0_kernel(const float* __restrict__ x, const int* __restrict__ rs,
                          unsigned short* __restrict__ t0) {
    int i = blockIdx.x * 256 + threadIdx.x;   // over NN*16 quads
    int n = i >> 4;
    float di = rsqrtf((float)(rs[n + 1] - rs[n]) + 1.0f);
    float4 v = ((const float4*)x)[i];
    ushort4 o;
    o.x = f2bf(v.x * di); o.y = f2bf(v.y * di);
    o.z = f2bf(v.z * di); o.w = f2bf(v.w * di);
    ((ushort4*)t0)[i] = o;
}

// Fused layer: u = t[n] + sum_nbr t[src] (bf16 gather, fp32 acc); v = dis*u;
// h' = v@W + b (fp32 LDS GEMM); tout = bf16(dis*h'); pooled[batch[n]] += h'.
// Register discipline (rounds 5-8 lessons):
//  - NO __launch_bounds__ min-waves demand (allocator spills to meet it: 1-2.4 GB scratch)
//  - s-loop serialized: #pragma unroll interleaved the 4 gather loops -> 144 VGPR -> 11% occ
//  - no dynamic-indexed local arrays (dis[] recomputed in epilogue, not stored)
__global__ __launch_bounds__(256)
void layer_kernel(const unsigned short* __restrict__ t, const int* __restrict__ csr,
                  const int* __restrict__ rs, const float* __restrict__ W,
                  const float* __restrict__ bias, const int* __restrict__ batch,
                  unsigned short* __restrict__ tout, float* __restrict__ pooled,
                  int l, int last) {
    __shared__ float Wsh[64 * 64];
    __shared__ float vsh[4][4][64];
    int tid = threadIdx.x;
    // bijective XCD chunk-swizzle
    int nwg = gridDim.x;                 // 6250
    int q = nwg >> 3, r = nwg & 7;       // 781, 2
    int xcd = blockIdx.x & 7, sub = blockIdx.x >> 3;
    int bid = (xcd < r ? xcd * (q + 1) : r * (q + 1) + (xcd - r) * q) + sub;

    #pragma unroll
    for (int i = 0; i < 16; ++i) Wsh[tid + i * 256] = W[tid + i * 256];

    int w = tid >> 6, lane = tid & 63;
    int n0 = bid * 16 + w * 4;
    #pragma clang loop unroll(disable)
    for (int s = 0; s < 4; ++s) {                // serialized: one gather loop live
        int n = n0 + s;
        int j0 = rs[n], j1 = rs[n + 1];
        float di = rsqrtf((float)(j1 - j0) + 1.0f);
        float acc = bf2f(t[n * 64 + lane]);
        int j = j0;
        #pragma clang loop unroll(disable)
        for (; j + 3 < j1; j += 4) {             // 4 gather lines in flight
            int i0 = csr[j], i1 = csr[j + 1], i2 = csr[j + 2], i3 = csr[j + 3];
            float v0 = bf2f(t[i0 * 64 + lane]);
            float v1 = bf2f(t[i1 * 64 + lane]);
            float v2 = bf2f(t[i2 * 64 + lane]);
            float v3 = bf2f(t[i3 * 64 + lane]);
            acc += (v0 + v1) + (v2 + v3);
        }
        #pragma clang loop unroll(disable)
        for (; j < j1; ++j) acc += bf2f(t[csr[j] * 64 + lane]);
        vsh[w][s][lane] = acc * di;
    }
    __syncthreads();
    float a0 = 0.f, a1 = 0.f, a2 = 0.f, a3 = 0.f;
    #pragma unroll
    for (int k = 0; k < 64; ++k) {
        float wv = Wsh[k * 64 + lane];
        a0 = fmaf(vsh[w][0][k], wv, a0);
        a1 = fmaf(vsh[w][1][k], wv, a1);
        a2 = fmaf(vsh[w][2][k], wv, a2);
        a3 = fmaf(vsh[w][3][k], wv, a3);
    }
    float bd = bias[lane];
    float accs[4] = {a0, a1, a2, a3};
    #pragma unroll
    for (int s = 0; s < 4; ++s) {
        int n = n0 + s;
        float h = accs[s] + bd;
        if (!last) {
            float di = rsqrtf((float)(rs[n + 1] - rs[n]) + 1.0f);  // recompute, L2-hot
            tout[n * 64 + lane] = f2bf(h * di);
        }
        atomicAdd(&pooled[batch[n] * 256 + l * 64 + lane], h);
    }
}

__global__ void mlp1_kernel(const float* __restrict__ pooled, const float* __restrict__ W1,
                            const float* __restrict__ b1, float* __restrict__ z1,
                            float* __restrict__ sums) {
    __shared__ float row[256];
    int g = blockIdx.x, d = threadIdx.x;   // 64 threads
    #pragma unroll
    for (int i = 0; i < 4; ++i) row[d + i * 64] = pooled[g * 256 + d + i * 64];
    __syncthreads();
    float acc = b1[d];
    #pragma unroll 8
    for (int k = 0; k < 256; ++k) acc = fmaf(row[k], W1[k * 64 + d], acc);
    z1[g * 64 + d] = acc;
    atomicAdd(&sums[d], acc);
    atomicAdd(&sums[64 + d], acc * acc);
}

__global__ void mlp2_kernel(const float* __restrict__ z1, const float* __restrict__ sums,
                            const float* __restrict__ gamma, const float* __restrict__ beta,
                            const float* __restrict__ W2, const float* __restrict__ b2,
                            float* __restrict__ out) {
    int g = blockIdx.x, d = threadIdx.x;   // 64 threads = 1 wave
    float mean = sums[d] * (1.0f / 512.0f);
    float var  = sums[64 + d] * (1.0f / 512.0f) - mean * mean;
    float z = (z1[g * 64 + d] - mean) * rsqrtf(var + EPSV) * gamma[d] + beta[d];
    z = fmaxf(z, 0.0f);
    #pragma unroll
    for (int o = 0; o < OUTC; ++o) {
        float v = z * W2[d * OUTC + o];
        #pragma unroll
        for (int s = 32; s; s >>= 1) v += __shfl_xor(v, s, 64);
        if (d == 0) out[g * OUTC + o] = v + b2[o];
    }
}

extern "C" void kernel_launch(void* const* d_in, const int* in_sizes, int n_in,
                              void* d_out, int out_size, void* d_ws, size_t ws_size,
                              hipStream_t stream) {
    (void)in_sizes; (void)n_in; (void)out_size; (void)ws_size;
    const float* x     = (const float*)d_in[0];
    const int*   ei    = (const int*)d_in[1];
    const int*   src   = ei;
    const int*   dst   = ei + NE;
    const int*   batch = (const int*)d_in[2];
    const float* Wc    = (const float*)d_in[3];
    const float* bc    = (const float*)d_in[4];
    const float* W1    = (const float*)d_in[5];
    const float* b1    = (const float*)d_in[6];
    const float* gamma = (const float*)d_in[7];
    const float* beta  = (const float*)d_in[8];
    const float* W2    = (const float*)d_in[9];
    const float* b2    = (const float*)d_in[10];
    float* out = (float*)d_out;
    float* ws  = (float*)d_ws;

    int*   rs     = (int*)(ws + OFF_RS);
    int*   csr    = (int*)(ws + OFF_CSR);
    int*   loc    = (int*)(ws + OFF_CSR);           // scan temp, dead before fill
    unsigned short* bufA = (unsigned short*)(ws + OFF_BUFA);
    unsigned short* bufB = (unsigned short*)(ws + OFF_BUFB);
    float* pooled = ws + OFF_POOL;
    int*   degcnt = (int*)(ws + OFF_POOL);          // deg, then cnt (dead before pooling)
    int*   bsum   = (int*)(ws + OFF_BUFA);          // scan temps, dead before t0
    int*   boff   = (int*)(ws + OFF_BUFA) + 128;
    float* z1     = ws + OFF_BUFA;                  // overlay, after layers
    float* sums   = ws + OFF_BUFA + GG * DD;

    // --- build CSR ---
    hipMemsetAsync(degcnt, 0, NN * sizeof(int), stream);
    deg_part_kernel<<<1024, 256, 0, stream>>>(dst, degcnt);
    scan1_kernel<<<98, 1024, 0, stream>>>(degcnt, loc, bsum);
    scan2_kernel<<<1, 128, 0, stream>>>(bsum, boff);
    scan3_kernel<<<99, 1024, 0, stream>>>(loc, boff, rs);
    hipMemsetAsync(degcnt, 0, NN * sizeof(int), stream);   // cnt
    fill_part_kernel<<<1024, 256, 0, stream>>>(src, dst, rs, degcnt, csr);

    // --- t0 = bf16(x * dis) ; zero pooled (overlays dead deg/cnt) ---
    t0_kernel<<<NN * 16 / 256, 256, 0, stream>>>(x, rs, bufA);
    hipMemsetAsync(pooled, 0, GG * LL * DD * sizeof(float), stream);

    // --- fused layers (ping-pong) ---
    unsigned short* tin = bufA; unsigned short* tot = bufB;
    for (int l = 0; l < LL; ++l) {
        layer_kernel<<<NN / 16, 256, 0, stream>>>(tin, csr, rs, Wc + l * 4096,
                                                  bc + l * 64, batch, tot, pooled,
                                                  l, l == LL - 1);
        unsigned short* tmp = tin; tin = tot; tot = tmp;
    }

    // --- MLP head (z1/sums overlay dead bufA) ---
    hipMemsetAsync(sums, 0, 128 * sizeof(float), stream);
    mlp1_kernel<<<GG, 64, 0, stream>>>(pooled, W1, b1, z1, sums);
    mlp2_kernel<<<GG, 64, 0, stream>>>(z1, sums, gamma, beta, W2, b2, out);
}

// Round 10
// 1596.922 us; speedup vs baseline: 1.1478x; 1.1478x over previous
//
#include <hip/hip_runtime.h>

#define NN   100000
#define NE   1600000
#define DD   64
#define LL   4
#define GG   512
#define OUTC 10
#define EPSV 1e-5f
#define PARTSZ 12500   // NN/8 dst-partition size

// workspace layout (float offsets). Total 14,631,088 floats = 58.5 MB.
#define OFF_RS    0          // int row_start[NN+1]
#define OFF_CSR   100016     // int csr_src[NE]   (first NN ints double as scan temp 'loc')
#define OFF_BUFA  1700016    // bf16 t ping (uses half the region; z1/sums/scan temps overlay)
#define OFF_BUFB  8100016    // bf16 t pong
#define OFF_POOL  14500016   // float pooled[GG*LL*DD]; deg/cnt(int[NN]) overlay pre-layers

static __device__ __forceinline__ unsigned short f2bf(float f) {
    unsigned int u = __float_as_uint(f);
    unsigned int r = (u + 0x7fffu + ((u >> 16) & 1u)) >> 16;   // RNE, finite inputs
    return (unsigned short)r;
}
// packed-pair unpack: free (shift/mask + reinterpret)
static __device__ __forceinline__ float plo(unsigned int v) {
    return __uint_as_float(v << 16);
}
static __device__ __forceinline__ float phi(unsigned int v) {
    return __uint_as_float(v & 0xffff0000u);
}

// ---- CSR build: XCD-partitioned histogram + fill ----
__global__ void deg_part_kernel(const int* __restrict__ dst, int* __restrict__ deg) {
    int p   = blockIdx.x & 7;
    int sub = blockIdx.x >> 3;
    int nb  = gridDim.x >> 3;
    for (int e = sub * 256 + threadIdx.x; e < NE; e += nb * 256) {
        int d = dst[e];
        if (d / PARTSZ == p) atomicAdd(&deg[d], 1);
    }
}

__global__ void scan1_kernel(const int* __restrict__ deg, int* __restrict__ loc,
                             int* __restrict__ bsum) {
    int t = threadIdx.x;
    int i = blockIdx.x * 1024 + t;
    int v = (i < NN) ? deg[i] : 0;
    __shared__ int ps[1024];
    ps[t] = v;
    __syncthreads();
    #pragma unroll
    for (int off = 1; off < 1024; off <<= 1) {
        int u = (t >= off) ? ps[t - off] : 0;
        __syncthreads();
        ps[t] += u;
        __syncthreads();
    }
    if (i < NN) loc[i] = ps[t] - v;
    if (t == 1023) bsum[blockIdx.x] = ps[1023];
}

__global__ void scan2_kernel(const int* __restrict__ bsum, int* __restrict__ boff) {
    int t = threadIdx.x;                      // 128 threads, 98 valid
    int v = (t < 98) ? bsum[t] : 0;
    __shared__ int ps[128];
    ps[t] = v;
    __syncthreads();
    #pragma unroll
    for (int off = 1; off < 128; off <<= 1) {
        int u = (t >= off) ? ps[t - off] : 0;
        __syncthreads();
        ps[t] += u;
        __syncthreads();
    }
    if (t < 98) boff[t] = ps[t] - v;
    if (t == 127) boff[98] = ps[127];
}

__global__ void scan3_kernel(const int* __restrict__ loc, const int* __restrict__ boff,
                             int* __restrict__ rs) {
    int i = blockIdx.x * 1024 + threadIdx.x;
    if (i < NN) rs[i] = loc[i] + boff[i >> 10];
    if (i == NN) rs[NN] = boff[98];
}

__global__ void fill_part_kernel(const int* __restrict__ src, const int* __restrict__ dst,
                                 const int* __restrict__ rs, int* __restrict__ cnt,
                                 int* __restrict__ csr) {
    int p   = blockIdx.x & 7;
    int sub = blockIdx.x >> 3;
    int nb  = gridDim.x >> 3;
    for (int e = sub * 256 + threadIdx.x; e < NE; e += nb * 256) {
        int d = dst[e];
        if (d / PARTSZ == p) {
            int slot = rs[d] + atomicAdd(&cnt[d], 1);
            csr[slot] = src[e];
        }
    }
}

// t0 = bf16(x * deg^{-1/2}); 4 elements/thread
__global__ void t0_kernel(const float* __restrict__ x, const int* __restrict__ rs,
                          unsigned short* __restrict__ t0) {
    int i = blockIdx.x * 256 + threadIdx.x;   // over NN*16 quads
    int n = i >> 4;
    float di = rsqrtf((float)(rs[n + 1] - rs[n]) + 1.0f);
    float4 v = ((const float4*)x)[i];
    ushort4 o;
    o.x = f2bf(v.x * di); o.y = f2bf(v.y * di);
    o.z = f2bf(v.z * di); o.w = f2bf(v.w * di);
    ((ushort4*)t0)[i] = o;
}

// Fused layer, packed-pair wave-cooperative gather (round-10 restructure):
// t rows are 32 uints (2 bf16 each) = 128 B = 1 cache line. Wave splits:
// h=lane>>5 picks neighbor j+h, c=lane&31 picks the uint -> one load insn
// fetches TWO rows; each lane keeps only 2 fp32 accumulators. Cross-half
// combine via shfl_xor(32). This bounds per-lane state (~30 VGPR) by
// construction -- rounds 5-9 showed source pragmas cannot stop the backend
// from inflating the per-lane-scalar-gather to 136-144 VGPR / 11% occupancy.
__global__ __launch_bounds__(256)
void layer_kernel(const unsigned short* __restrict__ t, const int* __restrict__ csr,
                  const int* __restrict__ rs, const float* __restrict__ W,
                  const float* __restrict__ bias, const int* __restrict__ batch,
                  unsigned short* __restrict__ tout, float* __restrict__ pooled,
                  int l, int last) {
    __shared__ float Wsh[64 * 64];
    __shared__ float vsh[4][4][64];
    const unsigned int* tu = (const unsigned int*)t;
    int tid = threadIdx.x;
    // bijective XCD chunk-swizzle
    int nwg = gridDim.x;                 // 6250
    int q = nwg >> 3, r = nwg & 7;       // 781, 2
    int xcd = blockIdx.x & 7, sub = blockIdx.x >> 3;
    int bid = (xcd < r ? xcd * (q + 1) : r * (q + 1) + (xcd - r) * q) + sub;

    #pragma unroll
    for (int i = 0; i < 16; ++i) Wsh[tid + i * 256] = W[tid + i * 256];

    int w = tid >> 6, lane = tid & 63;
    int h = lane >> 5;                   // which neighbor of the pair
    int c = lane & 31;                   // which uint (channels 2c, 2c+1)
    int n0 = bid * 16 + w * 4;

    #pragma clang loop unroll(disable)
    for (int s = 0; s < 4; ++s) {
        int n = n0 + s;
        int j0 = rs[n], j1 = rs[n + 1];
        float di = rsqrtf((float)(j1 - j0) + 1.0f);
        float alo = 0.f, ahi = 0.f;
        if (h == 0) {                    // self row, counted once
            unsigned int v = tu[n * 32 + c];
            alo = plo(v); ahi = phi(v);
        }
        int j = j0;
        #pragma clang loop unroll(disable)
        for (; j + 7 < j1; j += 8) {     // 4 pair-loads in flight = 8 rows
            int i0 = csr[j + h],     i1 = csr[j + 2 + h];
            int i2 = csr[j + 4 + h], i3 = csr[j + 6 + h];
            unsigned int v0 = tu[i0 * 32 + c];
            unsigned int v1 = tu[i1 * 32 + c];
            unsigned int v2 = tu[i2 * 32 + c];
            unsigned int v3 = tu[i3 * 32 + c];
            alo += (plo(v0) + plo(v1)) + (plo(v2) + plo(v3));
            ahi += (phi(v0) + phi(v1)) + (phi(v2) + phi(v3));
        }
        #pragma clang loop unroll(disable)
        for (; j + 1 < j1; j += 2) {
            unsigned int v0 = tu[csr[j + h] * 32 + c];
            alo += plo(v0); ahi += phi(v0);
        }
        if (j < j1 && h == 0) {          // odd tail: one row, h=0 half only
            unsigned int v0 = tu[csr[j] * 32 + c];
            alo += plo(v0); ahi += phi(v0);
        }
        alo += __shfl_xor(alo, 32, 64);
        ahi += __shfl_xor(ahi, 32, 64);
        if (h == 0) {
            vsh[w][s][2 * c]     = alo * di;
            vsh[w][s][2 * c + 1] = ahi * di;
        }
    }
    __syncthreads();
    float a0 = 0.f, a1 = 0.f, a2 = 0.f, a3 = 0.f;
    #pragma unroll
    for (int k = 0; k < 64; ++k) {
        float wv = Wsh[k * 64 + lane];
        a0 = fmaf(vsh[w][0][k], wv, a0);
        a1 = fmaf(vsh[w][1][k], wv, a1);
        a2 = fmaf(vsh[w][2][k], wv, a2);
        a3 = fmaf(vsh[w][3][k], wv, a3);
    }
    float bd = bias[lane];
    float accs[4] = {a0, a1, a2, a3};
    #pragma unroll
    for (int s = 0; s < 4; ++s) {
        int n = n0 + s;
        float hv = accs[s] + bd;
        if (!last) {
            float di = rsqrtf((float)(rs[n + 1] - rs[n]) + 1.0f);  // recompute, L2-hot
            tout[n * 64 + lane] = f2bf(hv * di);
        }
        atomicAdd(&pooled[batch[n] * 256 + l * 64 + lane], hv);
    }
}

__global__ void mlp1_kernel(const float* __restrict__ pooled, const float* __restrict__ W1,
                            const float* __restrict__ b1, float* __restrict__ z1,
                            float* __restrict__ sums) {
    __shared__ float row[256];
    int g = blockIdx.x, d = threadIdx.x;   // 64 threads
    #pragma unroll
    for (int i = 0; i < 4; ++i) row[d + i * 64] = pooled[g * 256 + d + i * 64];
    __syncthreads();
    float acc = b1[d];
    #pragma unroll 8
    for (int k = 0; k < 256; ++k) acc = fmaf(row[k], W1[k * 64 + d], acc);
    z1[g * 64 + d] = acc;
    atomicAdd(&sums[d], acc);
    atomicAdd(&sums[64 + d], acc * acc);
}

__global__ void mlp2_kernel(const float* __restrict__ z1, const float* __restrict__ sums,
                            const float* __restrict__ gamma, const float* __restrict__ beta,
                            const float* __restrict__ W2, const float* __restrict__ b2,
                            float* __restrict__ out) {
    int g = blockIdx.x, d = threadIdx.x;   // 64 threads = 1 wave
    float mean = sums[d] * (1.0f / 512.0f);
    float var  = sums[64 + d] * (1.0f / 512.0f) - mean * mean;
    float z = (z1[g * 64 + d] - mean) * rsqrtf(var + EPSV) * gamma[d] + beta[d];
    z = fmaxf(z, 0.0f);
    #pragma unroll
    for (int o = 0; o < OUTC; ++o) {
        float v = z * W2[d * OUTC + o];
        #pragma unroll
        for (int s = 32; s; s >>= 1) v += __shfl_xor(v, s, 64);
        if (d == 0) out[g * OUTC + o] = v + b2[o];
    }
}

extern "C" void kernel_launch(void* const* d_in, const int* in_sizes, int n_in,
                              void* d_out, int out_size, void* d_ws, size_t ws_size,
                              hipStream_t stream) {
    (void)in_sizes; (void)n_in; (void)out_size; (void)ws_size;
    const float* x     = (const float*)d_in[0];
    const int*   ei    = (const int*)d_in[1];
    const int*   src   = ei;
    const int*   dst   = ei + NE;
    const int*   batch = (const int*)d_in[2];
    const float* Wc    = (const float*)d_in[3];
    const float* bc    = (const float*)d_in[4];
    const float* W1    = (const float*)d_in[5];
    const float* b1    = (const float*)d_in[6];
    const float* gamma = (const float*)d_in[7];
    const float* beta  = (const float*)d_in[8];
    const float* W2    = (const float*)d_in[9];
    const float* b2    = (const float*)d_in[10];
    float* out = (float*)d_out;
    float* ws  = (float*)d_ws;

    int*   rs     = (int*)(ws + OFF_RS);
    int*   csr    = (int*)(ws + OFF_CSR);
    int*   loc    = (int*)(ws + OFF_CSR);           // scan temp, dead before fill
    unsigned short* bufA = (unsigned short*)(ws + OFF_BUFA);
    unsigned short* bufB = (unsigned short*)(ws + OFF_BUFB);
    float* pooled = ws + OFF_POOL;
    int*   degcnt = (int*)(ws + OFF_POOL);          // deg, then cnt (dead before pooling)
    int*   bsum   = (int*)(ws + OFF_BUFA);          // scan temps, dead before t0
    int*   boff   = (int*)(ws + OFF_BUFA) + 128;
    float* z1     = ws + OFF_BUFA;                  // overlay, after layers
    float* sums   = ws + OFF_BUFA + GG * DD;

    // --- build CSR ---
    hipMemsetAsync(degcnt, 0, NN * sizeof(int), stream);
    deg_part_kernel<<<1024, 256, 0, stream>>>(dst, degcnt);
    scan1_kernel<<<98, 1024, 0, stream>>>(degcnt, loc, bsum);
    scan2_kernel<<<1, 128, 0, stream>>>(bsum, boff);
    scan3_kernel<<<99, 1024, 0, stream>>>(loc, boff, rs);
    hipMemsetAsync(degcnt, 0, NN * sizeof(int), stream);   // cnt
    fill_part_kernel<<<1024, 256, 0, stream>>>(src, dst, rs, degcnt, csr);

    // --- t0 = bf16(x * dis) ; zero pooled (overlays dead deg/cnt) ---
    t0_kernel<<<NN * 16 / 256, 256, 0, stream>>>(x, rs, bufA);
    hipMemsetAsync(pooled, 0, GG * LL * DD * sizeof(float), stream);

    // --- fused layers (ping-pong) ---
    unsigned short* tin = bufA; unsigned short* tot = bufB;
    for (int l = 0; l < LL; ++l) {
        layer_kernel<<<NN / 16, 256, 0, stream>>>(tin, csr, rs, Wc + l * 4096,
                                                  bc + l * 64, batch, tot, pooled,
                                                  l, l == LL - 1);
        unsigned short* tmp = tin; tin = tot; tot = tmp;
    }

    // --- MLP head (z1/sums overlay dead bufA) ---
    hipMemsetAsync(sums, 0, 128 * sizeof(float), stream);
    mlp1_kernel<<<GG, 64, 0, stream>>>(pooled, W1, b1, z1, sums);
    mlp2_kernel<<<GG, 64, 0, stream>>>(z1, sums, gamma, beta, W2, b2, out);
}

// Round 11
// 639.064 us; speedup vs baseline: 2.8681x; 2.4988x over previous
//
#include <hip/hip_runtime.h>

#define NN   100000
#define NE   1600000
#define DD   64
#define LL   4
#define GG   512
#define OUTC 10
#define EPSV 1e-5f
#define PARTSZ 12500   // NN/8 dst-partition size

// workspace layout (float offsets). Total 14,631,088 floats = 58.5 MB.
#define OFF_RS    0          // int row_start[NN+1]
#define OFF_CSR   100016     // int csr_src[NE]
#define OFF_BUFA  1700016    // bf16 t ping (first half) + bf16 v (second half)
#define OFF_BUFB  8100016    // bf16 t pong
#define OFF_POOL  14500016   // float pooled[GG*LL*DD]; deg/cnt(int[NN]) overlay pre-layers

static __device__ __forceinline__ unsigned short f2bf(float f) {
    unsigned int u = __float_as_uint(f);
    unsigned int r = (u + 0x7fffu + ((u >> 16) & 1u)) >> 16;   // RNE, finite inputs
    return (unsigned short)r;
}
static __device__ __forceinline__ float plo(unsigned int v) {
    return __uint_as_float(v << 16);
}
static __device__ __forceinline__ float phi(unsigned int v) {
    return __uint_as_float(v & 0xffff0000u);
}

// ---- CSR build: XCD-partitioned histogram + fill ----
__global__ void deg_part_kernel(const int* __restrict__ dst, int* __restrict__ deg) {
    int p   = blockIdx.x & 7;
    int sub = blockIdx.x >> 3;
    int nb  = gridDim.x >> 3;
    for (int e = sub * 256 + threadIdx.x; e < NE; e += nb * 256) {
        int d = dst[e];
        if (d / PARTSZ == p) atomicAdd(&deg[d], 1);
    }
}

__global__ void scan1_kernel(const int* __restrict__ deg, int* __restrict__ loc,
                             int* __restrict__ bsum) {
    int t = threadIdx.x;
    int i = blockIdx.x * 1024 + t;
    int v = (i < NN) ? deg[i] : 0;
    __shared__ int ps[1024];
    ps[t] = v;
    __syncthreads();
    #pragma unroll
    for (int off = 1; off < 1024; off <<= 1) {
        int u = (t >= off) ? ps[t - off] : 0;
        __syncthreads();
        ps[t] += u;
        __syncthreads();
    }
    if (i < NN) loc[i] = ps[t] - v;
    if (t == 1023) bsum[blockIdx.x] = ps[1023];
}

__global__ void scan2_kernel(const int* __restrict__ bsum, int* __restrict__ boff) {
    int t = threadIdx.x;                      // 128 threads, 98 valid
    int v = (t < 98) ? bsum[t] : 0;
    __shared__ int ps[128];
    ps[t] = v;
    __syncthreads();
    #pragma unroll
    for (int off = 1; off < 128; off <<= 1) {
        int u = (t >= off) ? ps[t - off] : 0;
        __syncthreads();
        ps[t] += u;
        __syncthreads();
    }
    if (t < 98) boff[t] = ps[t] - v;
    if (t == 127) boff[98] = ps[127];
}

__global__ void scan3_kernel(const int* __restrict__ loc, const int* __restrict__ boff,
                             int* __restrict__ rs) {
    int i = blockIdx.x * 1024 + threadIdx.x;
    if (i < NN) rs[i] = loc[i] + boff[i >> 10];
    if (i == NN) rs[NN] = boff[98];
}

__global__ void fill_part_kernel(const int* __restrict__ src, const int* __restrict__ dst,
                                 const int* __restrict__ rs, int* __restrict__ cnt,
                                 int* __restrict__ csr) {
    int p   = blockIdx.x & 7;
    int sub = blockIdx.x >> 3;
    int nb  = gridDim.x >> 3;
    for (int e = sub * 256 + threadIdx.x; e < NE; e += nb * 256) {
        int d = dst[e];
        if (d / PARTSZ == p) {
            int slot = rs[d] + atomicAdd(&cnt[d], 1);
            csr[slot] = src[e];
        }
    }
}

// t0 = bf16(x * deg^{-1/2}); 4 elements/thread
__global__ void t0_kernel(const float* __restrict__ x, const int* __restrict__ rs,
                          unsigned short* __restrict__ t0) {
    int i = blockIdx.x * 256 + threadIdx.x;   // over NN*16 quads
    int n = i >> 4;
    float di = rsqrtf((float)(rs[n + 1] - rs[n]) + 1.0f);
    float4 v = ((const float4*)x)[i];
    ushort4 o;
    o.x = f2bf(v.x * di); o.y = f2bf(v.y * di);
    o.z = f2bf(v.z * di); o.w = f2bf(v.w * di);
    ((ushort4*)t0)[i] = o;
}

// Gather ONLY (split from GEMM so register allocation is bounded by this tiny
// body): v[n] = bf16( dis[n] * (t[n] + sum_nbr t[src]) ).
// Quarter-wave per node: 16 lanes, lane l owns channels 4l..4l+3 via uint2 —
// one wave load = 4 whole rows; 4 nodes/wave progress in PARALLEL.
__global__ __launch_bounds__(256)
void gather_kernel(const unsigned short* __restrict__ t, const int* __restrict__ csr,
                   const int* __restrict__ rs, unsigned short* __restrict__ vout) {
    const uint2* tu2 = (const uint2*)t;
    uint2* vo2 = (uint2*)vout;
    int tid = threadIdx.x;
    // bijective XCD chunk-swizzle
    int nwg = gridDim.x;                 // 6250
    int q = nwg >> 3, r = nwg & 7;       // 781, 2
    int xcd = blockIdx.x & 7, sub = blockIdx.x >> 3;
    int bid = (xcd < r ? xcd * (q + 1) : r * (q + 1) + (xcd - r) * q) + sub;

    int n = bid * 16 + (tid >> 4);       // quarter-wave -> node
    int l = tid & 15;                    // uint2 index: channels 4l..4l+3
    int j0 = rs[n], j1 = rs[n + 1];
    float di = rsqrtf((float)(j1 - j0) + 1.0f);

    uint2 sv = tu2[n * 16 + l];          // self row
    float a0 = plo(sv.x), a1 = phi(sv.x), a2 = plo(sv.y), a3 = phi(sv.y);

    int j = j0;
    #pragma clang loop unroll(disable)
    for (; j + 3 < j1; j += 4) {         // 4 rows in flight per quarter
        int i0 = csr[j], i1 = csr[j + 1], i2 = csr[j + 2], i3 = csr[j + 3];
        uint2 v0 = tu2[i0 * 16 + l];
        uint2 v1 = tu2[i1 * 16 + l];
        uint2 v2 = tu2[i2 * 16 + l];
        uint2 v3 = tu2[i3 * 16 + l];
        a0 += (plo(v0.x) + plo(v1.x)) + (plo(v2.x) + plo(v3.x));
        a1 += (phi(v0.x) + phi(v1.x)) + (phi(v2.x) + phi(v3.x));
        a2 += (plo(v0.y) + plo(v1.y)) + (plo(v2.y) + plo(v3.y));
        a3 += (phi(v0.y) + phi(v1.y)) + (phi(v2.y) + phi(v3.y));
    }
    #pragma clang loop unroll(disable)
    for (; j < j1; ++j) {
        uint2 v0 = tu2[csr[j] * 16 + l];
        a0 += plo(v0.x); a1 += phi(v0.x);
        a2 += plo(v0.y); a3 += phi(v0.y);
    }
    uint2 o;
    o.x = (unsigned int)f2bf(a0 * di) | ((unsigned int)f2bf(a1 * di) << 16);
    o.y = (unsigned int)f2bf(a2 * di) | ((unsigned int)f2bf(a3 * di) << 16);
    vo2[n * 16 + l] = o;
}

// GEMM + epilogue (linear streaming): h = v @ W + b; tout = bf16(dis*h);
// pooled[batch[n]] += h.  16 rows/block, 256 threads, round-2's known shape.
__global__ __launch_bounds__(256)
void vgemm_kernel(const unsigned short* __restrict__ v, const float* __restrict__ W,
                  const float* __restrict__ bias, const int* __restrict__ rs,
                  const int* __restrict__ batch, unsigned short* __restrict__ tout,
                  float* __restrict__ pooled, int l, int last) {
    __shared__ float Wsh[64 * 64];
    __shared__ float hs[16][64];
    const uint2* vu2 = (const uint2*)v;
    int tid = threadIdx.x;
    int row0 = blockIdx.x * 16;
    #pragma unroll
    for (int i = 0; i < 16; ++i) Wsh[tid + i * 256] = W[tid + i * 256];
    {
        int rr = tid >> 4, cc = tid & 15;        // one uint2 per thread = 4 ch
        uint2 u = vu2[(row0 + rr) * 16 + cc];
        hs[rr][4 * cc]     = plo(u.x);
        hs[rr][4 * cc + 1] = phi(u.x);
        hs[rr][4 * cc + 2] = plo(u.y);
        hs[rr][4 * cc + 3] = phi(u.y);
    }
    __syncthreads();
    int w = tid >> 6, d = tid & 63;
    float a0 = 0.f, a1 = 0.f, a2 = 0.f, a3 = 0.f;
    #pragma unroll
    for (int k = 0; k < 64; ++k) {
        float wv = Wsh[k * 64 + d];
        a0 = fmaf(hs[w * 4 + 0][k], wv, a0);
        a1 = fmaf(hs[w * 4 + 1][k], wv, a1);
        a2 = fmaf(hs[w * 4 + 2][k], wv, a2);
        a3 = fmaf(hs[w * 4 + 3][k], wv, a3);
    }
    float bd = bias[d];
    float accs[4] = {a0, a1, a2, a3};
    #pragma unroll
    for (int s = 0; s < 4; ++s) {
        int n = row0 + w * 4 + s;
        float h = accs[s] + bd;
        if (!last) {
            float di = rsqrtf((float)(rs[n + 1] - rs[n]) + 1.0f);
            tout[n * 64 + d] = f2bf(h * di);
        }
        atomicAdd(&pooled[batch[n] * 256 + l * 64 + d], h);
    }
}

__global__ void mlp1_kernel(const float* __restrict__ pooled, const float* __restrict__ W1,
                            const float* __restrict__ b1, float* __restrict__ z1,
                            float* __restrict__ sums) {
    __shared__ float row[256];
    int g = blockIdx.x, d = threadIdx.x;   // 64 threads
    #pragma unroll
    for (int i = 0; i < 4; ++i) row[d + i * 64] = pooled[g * 256 + d + i * 64];
    __syncthreads();
    float acc = b1[d];
    #pragma unroll 8
    for (int k = 0; k < 256; ++k) acc = fmaf(row[k], W1[k * 64 + d], acc);
    z1[g * 64 + d] = acc;
    atomicAdd(&sums[d], acc);
    atomicAdd(&sums[64 + d], acc * acc);
}

__global__ void mlp2_kernel(const float* __restrict__ z1, const float* __restrict__ sums,
                            const float* __restrict__ gamma, const float* __restrict__ beta,
                            const float* __restrict__ W2, const float* __restrict__ b2,
                            float* __restrict__ out) {
    int g = blockIdx.x, d = threadIdx.x;   // 64 threads = 1 wave
    float mean = sums[d] * (1.0f / 512.0f);
    float var  = sums[64 + d] * (1.0f / 512.0f) - mean * mean;
    float z = (z1[g * 64 + d] - mean) * rsqrtf(var + EPSV) * gamma[d] + beta[d];
    z = fmaxf(z, 0.0f);
    #pragma unroll
    for (int o = 0; o < OUTC; ++o) {
        float v = z * W2[d * OUTC + o];
        #pragma unroll
        for (int s = 32; s; s >>= 1) v += __shfl_xor(v, s, 64);
        if (d == 0) out[g * OUTC + o] = v + b2[o];
    }
}

extern "C" void kernel_launch(void* const* d_in, const int* in_sizes, int n_in,
                              void* d_out, int out_size, void* d_ws, size_t ws_size,
                              hipStream_t stream) {
    (void)in_sizes; (void)n_in; (void)out_size; (void)ws_size;
    const float* x     = (const float*)d_in[0];
    const int*   ei    = (const int*)d_in[1];
    const int*   src   = ei;
    const int*   dst   = ei + NE;
    const int*   batch = (const int*)d_in[2];
    const float* Wc    = (const float*)d_in[3];
    const float* bc    = (const float*)d_in[4];
    const float* W1    = (const float*)d_in[5];
    const float* b1    = (const float*)d_in[6];
    const float* gamma = (const float*)d_in[7];
    const float* beta  = (const float*)d_in[8];
    const float* W2    = (const float*)d_in[9];
    const float* b2    = (const float*)d_in[10];
    float* out = (float*)d_out;
    float* ws  = (float*)d_ws;

    int*   rs     = (int*)(ws + OFF_RS);
    int*   csr    = (int*)(ws + OFF_CSR);
    int*   loc    = (int*)(ws + OFF_CSR);           // scan temp, dead before fill
    unsigned short* tping = (unsigned short*)(ws + OFF_BUFA);
    unsigned short* vbuf  = tping + 6400000;        // second half of BUFA region
    unsigned short* tpong = (unsigned short*)(ws + OFF_BUFB);
    float* pooled = ws + OFF_POOL;
    int*   degcnt = (int*)(ws + OFF_POOL);          // deg, then cnt (dead before pooling)
    int*   bsum   = (int*)(ws + OFF_BUFA);          // scan temps, dead before t0
    int*   boff   = (int*)(ws + OFF_BUFA) + 128;
    float* z1     = ws + OFF_BUFA;                  // overlay, after layers
    float* sums   = ws + OFF_BUFA + GG * DD;

    // --- build CSR ---
    hipMemsetAsync(degcnt, 0, NN * sizeof(int), stream);
    deg_part_kernel<<<1024, 256, 0, stream>>>(dst, degcnt);
    scan1_kernel<<<98, 1024, 0, stream>>>(degcnt, loc, bsum);
    scan2_kernel<<<1, 128, 0, stream>>>(bsum, boff);
    scan3_kernel<<<99, 1024, 0, stream>>>(loc, boff, rs);
    hipMemsetAsync(degcnt, 0, NN * sizeof(int), stream);   // cnt
    fill_part_kernel<<<1024, 256, 0, stream>>>(src, dst, rs, degcnt, csr);

    // --- t0 = bf16(x * dis) ; zero pooled (overlays dead deg/cnt) ---
    t0_kernel<<<NN * 16 / 256, 256, 0, stream>>>(x, rs, tping);
    hipMemsetAsync(pooled, 0, GG * LL * DD * sizeof(float), stream);

    // --- layers: gather (latency-light) then linear GEMM ---
    unsigned short* tin = tping; unsigned short* tot = tpong;
    for (int l = 0; l < LL; ++l) {
        gather_kernel<<<NN / 16, 256, 0, stream>>>(tin, csr, rs, vbuf);
        vgemm_kernel<<<NN / 16, 256, 0, stream>>>(vbuf, Wc + l * 4096, bc + l * 64,
                                                  rs, batch, tot, pooled,
                                                  l, l == LL - 1);
        unsigned short* tmp = tin; tin = tot; tot = tmp;
    }

    // --- MLP head (z1/sums overlay dead BUFA region) ---
    hipMemsetAsync(sums, 0, 128 * sizeof(float), stream);
    mlp1_kernel<<<GG, 64, 0, stream>>>(pooled, W1, b1, z1, sums);
    mlp2_kernel<<<GG, 64, 0, stream>>>(z1, sums, gamma, beta, W2, b2, out);
}

// Round 12
// 492.993 us; speedup vs baseline: 3.7178x; 1.2963x over previous
//
#include <hip/hip_runtime.h>

#define NN   100000
#define NE   1600000
#define DD   64
#define LL   4
#define GG   512
#define OUTC 10
#define EPSV 1e-5f
#define PARTSZ 12500   // NN/8 dst-partition size

// workspace layout (float offsets). Total 14,631,088 floats = 58.5 MB.
#define OFF_RS    0          // int row_start[NN+1]
#define OFF_CSR   100016     // int csr_src[NE]
#define OFF_BUFA  1700016    // bf16 t ping (first half) + bf16 v (second half)
#define OFF_BUFB  8100016    // bf16 t pong
#define OFF_POOL  14500016   // float pooled[GG*LL*DD]; deg/cnt(int[NN]) overlay pre-layers

static __device__ __forceinline__ unsigned short f2bf(float f) {
    unsigned int u = __float_as_uint(f);
    unsigned int r = (u + 0x7fffu + ((u >> 16) & 1u)) >> 16;   // RNE, finite inputs
    return (unsigned short)r;
}
static __device__ __forceinline__ float plo(unsigned int v) {
    return __uint_as_float(v << 16);
}
static __device__ __forceinline__ float phi(unsigned int v) {
    return __uint_as_float(v & 0xffff0000u);
}

// ---- CSR build: XCD-partitioned histogram + fill ----
__global__ void deg_part_kernel(const int* __restrict__ dst, int* __restrict__ deg) {
    int p   = blockIdx.x & 7;
    int sub = blockIdx.x >> 3;
    int nb  = gridDim.x >> 3;
    for (int e = sub * 256 + threadIdx.x; e < NE; e += nb * 256) {
        int d = dst[e];
        if (d / PARTSZ == p) atomicAdd(&deg[d], 1);
    }
}

__global__ void scan1_kernel(const int* __restrict__ deg, int* __restrict__ loc,
                             int* __restrict__ bsum) {
    int t = threadIdx.x;
    int i = blockIdx.x * 1024 + t;
    int v = (i < NN) ? deg[i] : 0;
    __shared__ int ps[1024];
    ps[t] = v;
    __syncthreads();
    #pragma unroll
    for (int off = 1; off < 1024; off <<= 1) {
        int u = (t >= off) ? ps[t - off] : 0;
        __syncthreads();
        ps[t] += u;
        __syncthreads();
    }
    if (i < NN) loc[i] = ps[t] - v;
    if (t == 1023) bsum[blockIdx.x] = ps[1023];
}

__global__ void scan2_kernel(const int* __restrict__ bsum, int* __restrict__ boff) {
    int t = threadIdx.x;                      // 128 threads, 98 valid
    int v = (t < 98) ? bsum[t] : 0;
    __shared__ int ps[128];
    ps[t] = v;
    __syncthreads();
    #pragma unroll
    for (int off = 1; off < 128; off <<= 1) {
        int u = (t >= off) ? ps[t - off] : 0;
        __syncthreads();
        ps[t] += u;
        __syncthreads();
    }
    if (t < 98) boff[t] = ps[t] - v;
    if (t == 127) boff[98] = ps[127];
}

__global__ void scan3_kernel(const int* __restrict__ loc, const int* __restrict__ boff,
                             int* __restrict__ rs) {
    int i = blockIdx.x * 1024 + threadIdx.x;
    if (i < NN) rs[i] = loc[i] + boff[i >> 10];
    if (i == NN) rs[NN] = boff[98];
}

__global__ void fill_part_kernel(const int* __restrict__ src, const int* __restrict__ dst,
                                 const int* __restrict__ rs, int* __restrict__ cnt,
                                 int* __restrict__ csr) {
    int p   = blockIdx.x & 7;
    int sub = blockIdx.x >> 3;
    int nb  = gridDim.x >> 3;
    for (int e = sub * 256 + threadIdx.x; e < NE; e += nb * 256) {
        int d = dst[e];
        if (d / PARTSZ == p) {
            int slot = rs[d] + atomicAdd(&cnt[d], 1);
            csr[slot] = src[e];
        }
    }
}

// t0 = bf16(x * deg^{-1/2}); 4 elements/thread
__global__ void t0_kernel(const float* __restrict__ x, const int* __restrict__ rs,
                          unsigned short* __restrict__ t0) {
    int i = blockIdx.x * 256 + threadIdx.x;   // over NN*16 quads
    int n = i >> 4;
    float di = rsqrtf((float)(rs[n + 1] - rs[n]) + 1.0f);
    float4 v = ((const float4*)x)[i];
    ushort4 o;
    o.x = f2bf(v.x * di); o.y = f2bf(v.y * di);
    o.z = f2bf(v.z * di); o.w = f2bf(v.w * di);
    ((ushort4*)t0)[i] = o;
}

// Gather ONLY: v[n] = bf16( dis[n] * (t[n] + sum_nbr t[src]) ).
// Quarter-wave per node: 16 lanes, lane l owns channels 4l..4l+3 via uint2;
// 8 rows in flight per quarter-wave (single loop -> no s-loop interleave trap).
__global__ __launch_bounds__(256)
void gather_kernel(const unsigned short* __restrict__ t, const int* __restrict__ csr,
                   const int* __restrict__ rs, unsigned short* __restrict__ vout) {
    const uint2* tu2 = (const uint2*)t;
    uint2* vo2 = (uint2*)vout;
    int tid = threadIdx.x;
    // bijective XCD chunk-swizzle
    int nwg = gridDim.x;                 // 6250
    int q = nwg >> 3, r = nwg & 7;       // 781, 2
    int xcd = blockIdx.x & 7, sub = blockIdx.x >> 3;
    int bid = (xcd < r ? xcd * (q + 1) : r * (q + 1) + (xcd - r) * q) + sub;

    int n = bid * 16 + (tid >> 4);       // quarter-wave -> node
    int l = tid & 15;                    // uint2 index: channels 4l..4l+3
    int j0 = rs[n], j1 = rs[n + 1];
    float di = rsqrtf((float)(j1 - j0) + 1.0f);

    uint2 sv = tu2[n * 16 + l];          // self row
    float a0 = plo(sv.x), a1 = phi(sv.x), a2 = plo(sv.y), a3 = phi(sv.y);

    int j = j0;
    #pragma clang loop unroll(disable)
    for (; j + 7 < j1; j += 8) {         // 8 rows in flight per quarter
        int i0 = csr[j],     i1 = csr[j + 1], i2 = csr[j + 2], i3 = csr[j + 3];
        int i4 = csr[j + 4], i5 = csr[j + 5], i6 = csr[j + 6], i7 = csr[j + 7];
        uint2 v0 = tu2[i0 * 16 + l];
        uint2 v1 = tu2[i1 * 16 + l];
        uint2 v2 = tu2[i2 * 16 + l];
        uint2 v3 = tu2[i3 * 16 + l];
        uint2 v4 = tu2[i4 * 16 + l];
        uint2 v5 = tu2[i5 * 16 + l];
        uint2 v6 = tu2[i6 * 16 + l];
        uint2 v7 = tu2[i7 * 16 + l];
        a0 += ((plo(v0.x) + plo(v1.x)) + (plo(v2.x) + plo(v3.x)))
            + ((plo(v4.x) + plo(v5.x)) + (plo(v6.x) + plo(v7.x)));
        a1 += ((phi(v0.x) + phi(v1.x)) + (phi(v2.x) + phi(v3.x)))
            + ((phi(v4.x) + phi(v5.x)) + (phi(v6.x) + phi(v7.x)));
        a2 += ((plo(v0.y) + plo(v1.y)) + (plo(v2.y) + plo(v3.y)))
            + ((plo(v4.y) + plo(v5.y)) + (plo(v6.y) + plo(v7.y)));
        a3 += ((phi(v0.y) + phi(v1.y)) + (phi(v2.y) + phi(v3.y)))
            + ((phi(v4.y) + phi(v5.y)) + (phi(v6.y) + phi(v7.y)));
    }
    #pragma clang loop unroll(disable)
    for (; j + 3 < j1; j += 4) {
        int i0 = csr[j], i1 = csr[j + 1], i2 = csr[j + 2], i3 = csr[j + 3];
        uint2 v0 = tu2[i0 * 16 + l];
        uint2 v1 = tu2[i1 * 16 + l];
        uint2 v2 = tu2[i2 * 16 + l];
        uint2 v3 = tu2[i3 * 16 + l];
        a0 += (plo(v0.x) + plo(v1.x)) + (plo(v2.x) + plo(v3.x));
        a1 += (phi(v0.x) + phi(v1.x)) + (phi(v2.x) + phi(v3.x));
        a2 += (plo(v0.y) + plo(v1.y)) + (plo(v2.y) + plo(v3.y));
        a3 += (phi(v0.y) + phi(v1.y)) + (phi(v2.y) + phi(v3.y));
    }
    #pragma clang loop unroll(disable)
    for (; j < j1; ++j) {
        uint2 v0 = tu2[csr[j] * 16 + l];
        a0 += plo(v0.x); a1 += phi(v0.x);
        a2 += plo(v0.y); a3 += phi(v0.y);
    }
    uint2 o;
    o.x = (unsigned int)f2bf(a0 * di) | ((unsigned int)f2bf(a1 * di) << 16);
    o.y = (unsigned int)f2bf(a2 * di) | ((unsigned int)f2bf(a3 * di) << 16);
    vo2[n * 16 + l] = o;
}

// Persistent-W grid-stride GEMM + epilogue: h = v @ W + b; tout = bf16(dis*h);
// pooled[batch] += h with LDS cross-wave reduction (batch sorted -> ~92% of
// 16-row chunks are single-graph -> 64 atomics/chunk instead of 1024).
__global__ __launch_bounds__(256)
void vgemm_kernel(const unsigned short* __restrict__ v, const float* __restrict__ W,
                  const float* __restrict__ bias, const int* __restrict__ rs,
                  const int* __restrict__ batch, unsigned short* __restrict__ tout,
                  float* __restrict__ pooled, int l, int last) {
    __shared__ float Wsh[64 * 64];
    __shared__ float hs[16][64];
    __shared__ float red[4][64];
    const uint2* vu2 = (const uint2*)v;
    int tid = threadIdx.x;
    #pragma unroll
    for (int i = 0; i < 16; ++i) Wsh[tid + i * 256] = W[tid + i * 256];  // once/block
    int w = tid >> 6, d = tid & 63;
    float bd = bias[d];

    for (int c = blockIdx.x; c < NN / 16; c += gridDim.x) {
        int n0 = c * 16;
        {
            int rr = tid >> 4, cc = tid & 15;    // one uint2/thread = 4 channels
            uint2 u = vu2[(n0 + rr) * 16 + cc];
            hs[rr][4 * cc]     = plo(u.x);
            hs[rr][4 * cc + 1] = phi(u.x);
            hs[rr][4 * cc + 2] = plo(u.y);
            hs[rr][4 * cc + 3] = phi(u.y);
        }
        __syncthreads();
        float a0 = 0.f, a1 = 0.f, a2 = 0.f, a3 = 0.f;
        #pragma unroll 2
        for (int k4 = 0; k4 < 16; ++k4) {        // 4 b128 + 4 b32 LDS per 16 FMA
            float4 h0 = *(const float4*)&hs[w * 4 + 0][k4 * 4];
            float4 h1 = *(const float4*)&hs[w * 4 + 1][k4 * 4];
            float4 h2 = *(const float4*)&hs[w * 4 + 2][k4 * 4];
            float4 h3 = *(const float4*)&hs[w * 4 + 3][k4 * 4];
            float w0 = Wsh[(k4 * 4 + 0) * 64 + d];
            float w1 = Wsh[(k4 * 4 + 1) * 64 + d];
            float w2 = Wsh[(k4 * 4 + 2) * 64 + d];
            float w3 = Wsh[(k4 * 4 + 3) * 64 + d];
            a0 = fmaf(h0.x, w0, a0); a0 = fmaf(h0.y, w1, a0);
            a0 = fmaf(h0.z, w2, a0); a0 = fmaf(h0.w, w3, a0);
            a1 = fmaf(h1.x, w0, a1); a1 = fmaf(h1.y, w1, a1);
            a1 = fmaf(h1.z, w2, a1); a1 = fmaf(h1.w, w3, a1);
            a2 = fmaf(h2.x, w0, a2); a2 = fmaf(h2.y, w1, a2);
            a2 = fmaf(h2.z, w2, a2); a2 = fmaf(h2.w, w3, a2);
            a3 = fmaf(h3.x, w0, a3); a3 = fmaf(h3.y, w1, a3);
            a3 = fmaf(h3.z, w2, a3); a3 = fmaf(h3.w, w3, a3);
        }
        float accs[4] = {a0, a1, a2, a3};
        if (!last) {
            #pragma unroll
            for (int s = 0; s < 4; ++s) {
                int n = n0 + w * 4 + s;
                float di = rsqrtf((float)(rs[n + 1] - rs[n]) + 1.0f);
                tout[n * 64 + d] = f2bf((accs[s] + bd) * di);
            }
        }
        int glo = batch[n0], ghi = batch[n0 + 15];
        if (glo == ghi) {                         // block-uniform branch
            red[w][d] = ((a0 + a1) + (a2 + a3)) + 4.0f * bd;
            __syncthreads();
            if (w == 0) {
                float tot = (red[0][d] + red[1][d]) + (red[2][d] + red[3][d]);
                atomicAdd(&pooled[glo * 256 + l * 64 + d], tot);
            }
        } else {
            #pragma unroll
            for (int s = 0; s < 4; ++s) {
                int n = n0 + w * 4 + s;
                atomicAdd(&pooled[batch[n] * 256 + l * 64 + d], accs[s] + bd);
            }
        }
        __syncthreads();                          // hs/red reuse barrier
    }
}

__global__ void mlp1_kernel(const float* __restrict__ pooled, const float* __restrict__ W1,
                            const float* __restrict__ b1, float* __restrict__ z1,
                            float* __restrict__ sums) {
    __shared__ float row[256];
    int g = blockIdx.x, d = threadIdx.x;   // 64 threads
    #pragma unroll
    for (int i = 0; i < 4; ++i) row[d + i * 64] = pooled[g * 256 + d + i * 64];
    __syncthreads();
    float acc = b1[d];
    #pragma unroll 8
    for (int k = 0; k < 256; ++k) acc = fmaf(row[k], W1[k * 64 + d], acc);
    z1[g * 64 + d] = acc;
    atomicAdd(&sums[d], acc);
    atomicAdd(&sums[64 + d], acc * acc);
}

__global__ void mlp2_kernel(const float* __restrict__ z1, const float* __restrict__ sums,
                            const float* __restrict__ gamma, const float* __restrict__ beta,
                            const float* __restrict__ W2, const float* __restrict__ b2,
                            float* __restrict__ out) {
    int g = blockIdx.x, d = threadIdx.x;   // 64 threads = 1 wave
    float mean = sums[d] * (1.0f / 512.0f);
    float var  = sums[64 + d] * (1.0f / 512.0f) - mean * mean;
    float z = (z1[g * 64 + d] - mean) * rsqrtf(var + EPSV) * gamma[d] + beta[d];
    z = fmaxf(z, 0.0f);
    #pragma unroll
    for (int o = 0; o < OUTC; ++o) {
        float v = z * W2[d * OUTC + o];
        #pragma unroll
        for (int s = 32; s; s >>= 1) v += __shfl_xor(v, s, 64);
        if (d == 0) out[g * OUTC + o] = v + b2[o];
    }
}

extern "C" void kernel_launch(void* const* d_in, const int* in_sizes, int n_in,
                              void* d_out, int out_size, void* d_ws, size_t ws_size,
                              hipStream_t stream) {
    (void)in_sizes; (void)n_in; (void)out_size; (void)ws_size;
    const float* x     = (const float*)d_in[0];
    const int*   ei    = (const int*)d_in[1];
    const int*   src   = ei;
    const int*   dst   = ei + NE;
    const int*   batch = (const int*)d_in[2];
    const float* Wc    = (const float*)d_in[3];
    const float* bc    = (const float*)d_in[4];
    const float* W1    = (const float*)d_in[5];
    const float* b1    = (const float*)d_in[6];
    const float* gamma = (const float*)d_in[7];
    const float* beta  = (const float*)d_in[8];
    const float* W2    = (const float*)d_in[9];
    const float* b2    = (const float*)d_in[10];
    float* out = (float*)d_out;
    float* ws  = (float*)d_ws;

    int*   rs     = (int*)(ws + OFF_RS);
    int*   csr    = (int*)(ws + OFF_CSR);
    int*   loc    = (int*)(ws + OFF_CSR);           // scan temp, dead before fill
    unsigned short* tping = (unsigned short*)(ws + OFF_BUFA);
    unsigned short* vbuf  = tping + 6400000;        // second half of BUFA region
    unsigned short* tpong = (unsigned short*)(ws + OFF_BUFB);
    float* pooled = ws + OFF_POOL;
    int*   degcnt = (int*)(ws + OFF_POOL);          // deg, then cnt (dead before pooling)
    int*   bsum   = (int*)(ws + OFF_BUFA);          // scan temps, dead before t0
    int*   boff   = (int*)(ws + OFF_BUFA) + 128;
    float* z1     = ws + OFF_BUFA;                  // overlay, after layers
    float* sums   = ws + OFF_BUFA + GG * DD;

    // --- build CSR ---
    hipMemsetAsync(degcnt, 0, NN * sizeof(int), stream);
    deg_part_kernel<<<1024, 256, 0, stream>>>(dst, degcnt);
    scan1_kernel<<<98, 1024, 0, stream>>>(degcnt, loc, bsum);
    scan2_kernel<<<1, 128, 0, stream>>>(bsum, boff);
    scan3_kernel<<<99, 1024, 0, stream>>>(loc, boff, rs);
    hipMemsetAsync(degcnt, 0, NN * sizeof(int), stream);   // cnt
    fill_part_kernel<<<1024, 256, 0, stream>>>(src, dst, rs, degcnt, csr);

    // --- t0 = bf16(x * dis) ; zero pooled (overlays dead deg/cnt) ---
    t0_kernel<<<NN * 16 / 256, 256, 0, stream>>>(x, rs, tping);
    hipMemsetAsync(pooled, 0, GG * LL * DD * sizeof(float), stream);

    // --- layers: gather (latency-light) then persistent-W GEMM ---
    unsigned short* tin = tping; unsigned short* tot = tpong;
    for (int l = 0; l < LL; ++l) {
        gather_kernel<<<NN / 16, 256, 0, stream>>>(tin, csr, rs, vbuf);
        vgemm_kernel<<<1536, 256, 0, stream>>>(vbuf, Wc + l * 4096, bc + l * 64,
                                               rs, batch, tot, pooled,
                                               l, l == LL - 1);
        unsigned short* tmp = tin; tin = tot; tot = tmp;
    }

    // --- MLP head (z1/sums overlay dead BUFA region) ---
    hipMemsetAsync(sums, 0, 128 * sizeof(float), stream);
    mlp1_kernel<<<GG, 64, 0, stream>>>(pooled, W1, b1, z1, sums);
    mlp2_kernel<<<GG, 64, 0, stream>>>(z1, sums, gamma, beta, W2, b2, out);
}